// Round 5
// baseline (1172.465 us; speedup 1.0000x reference)
//
#include <hip/hip_runtime.h>
#include <hip/hip_bf16.h>

#define NN 50000
#define EE 1600000
#define DIN 768
#define NH 256

typedef unsigned short u16;
typedef unsigned int u32;

typedef __attribute__((ext_vector_type(8))) short short8;
typedef __attribute__((ext_vector_type(4))) float f32x4;

__device__ __forceinline__ float bf2f(u16 u) {
  union { u32 i; float f; } x; x.i = ((u32)u) << 16; return x.f;
}
__device__ __forceinline__ u16 f2bf(float f) {
  union { float f; u32 u; } x; x.f = f;
  u32 r = x.u + 0x7fff + ((x.u >> 16) & 1);  // RNE
  return (u16)(r >> 16);
}

// ---------------- fused prep: convert_x + hist + pack_wt ----------------
__global__ __launch_bounds__(256) void prep_kernel(
    const float* __restrict__ X, u16* __restrict__ Xb,
    const int* __restrict__ rA, const int* __restrict__ rB,
    int* __restrict__ cntA, int* __restrict__ cntB,
    const float* __restrict__ Wa, const float* __restrict__ Wb,
    const float* __restrict__ Wc, u16* __restrict__ Wt) {
  int b = blockIdx.x;
  if (b < 37500) {
    size_t idx = (size_t)b * 256 + threadIdx.x;
    float4 v = reinterpret_cast<const float4*>(X)[idx];
    ushort4 o;
    o.x = f2bf(v.x); o.y = f2bf(v.y); o.z = f2bf(v.z); o.w = f2bf(v.w);
    reinterpret_cast<ushort4*>(Xb)[idx] = o;
  } else if (b < 50000) {
    int e = (b - 37500) * 256 + threadIdx.x;
    if (e < EE) atomicAdd(&cntA[rA[e]], 1);
    else        atomicAdd(&cntB[rB[e - EE]], 1);
  } else {
    int idx = (b - 50000) * 256 + threadIdx.x;
    int n = idx / DIN, k = idx - n * DIN;
    const float* W = (n < 256) ? Wa : (n < 512) ? Wb : Wc;
    Wt[idx] = f2bf(W[(size_t)k * NH + (n & 255)]);
  }
}

// ---------------- 3-phase scan (both CSRs via blockIdx.y) ----------------
__global__ __launch_bounds__(256) void scan1(int* __restrict__ cntA, int* __restrict__ rsA,
                                             int* __restrict__ cntB, int* __restrict__ rsB,
                                             int* __restrict__ bsum) {
  int* cnt = (blockIdx.y == 0) ? cntA : cntB;
  int* rs  = (blockIdx.y == 0) ? rsA  : rsB;
  int* bs  = bsum + blockIdx.y * 98;
  __shared__ int wsum[4];
  int t = threadIdx.x, lane = t & 63, wid = t >> 6;
  int i0 = blockIdx.x * 512 + 2 * t;
  int v0 = (i0 < NN) ? cnt[i0] : 0;
  int v1 = (i0 + 1 < NN) ? cnt[i0 + 1] : 0;
  int s = v0 + v1;
  int sc = s;
#pragma unroll
  for (int off = 1; off < 64; off <<= 1) {
    int tv = __shfl_up(sc, off, 64);
    if (lane >= off) sc += tv;
  }
  if (lane == 63) wsum[wid] = sc;
  __syncthreads();
  int woff = 0;
  for (int w = 0; w < wid; ++w) woff += wsum[w];
  int excl = woff + sc - s;
  if (i0 < NN)     { cnt[i0] = excl;          rs[i0 + 1] = excl + v0; }
  if (i0 + 1 < NN) { cnt[i0 + 1] = excl + v0; rs[i0 + 2] = excl + v0 + v1; }
  if (t == 255) bs[blockIdx.x] = woff + sc;
  if (blockIdx.x == 0 && t == 0) rs[0] = 0;
}

__global__ __launch_bounds__(128) void scan2(int* __restrict__ bsum) {
  int* bs = bsum + blockIdx.y * 98;
  __shared__ int tmp[128];
  int t = threadIdx.x;
  int orig = (t < 98) ? bs[t] : 0;
  tmp[t] = orig;
  __syncthreads();
  for (int off = 1; off < 128; off <<= 1) {
    int v = (t >= off) ? tmp[t - off] : 0;
    __syncthreads();
    tmp[t] += v;
    __syncthreads();
  }
  if (t < 98) bs[t] = tmp[t] - orig;
}

__global__ __launch_bounds__(512) void scan3(int* __restrict__ cntA, int* __restrict__ rsA,
                                             int* __restrict__ cntB, int* __restrict__ rsB,
                                             const int* __restrict__ bsum) {
  int* cnt = (blockIdx.y == 0) ? cntA : cntB;
  int* rs  = (blockIdx.y == 0) ? rsA  : rsB;
  int off = bsum[blockIdx.y * 98 + blockIdx.x];
  int i = blockIdx.x * 512 + threadIdx.x;
  if (i < NN) { cnt[i] += off; rs[i + 1] += off; }
}

// ---------------- fused layer-1 MFMA GEMM + slice-partitioned scatter ----------------
#define TM 128
#define TN 128
#define TK 32
#define GEMM_BLKS 2346           // 6 * 391
#define NUNITS 1563              // chunks; 1563*2048 >= 2E
#define CHUNK 2048
#define TOT_BLKS (NUNITS * 16)   // unit of 16: 8 scatter slices + 8 gemm slots

__device__ __forceinline__ void gload16(const u16* g, u16* lds) {
  __builtin_amdgcn_global_load_lds((const __attribute__((address_space(1))) unsigned int*)g,
                                   (__attribute__((address_space(3))) unsigned int*)lds, 16, 0, 0);
}

__global__ __launch_bounds__(256) void gemm_scatter(
    const u16* __restrict__ Xb, const u16* __restrict__ Wt, const float* __restrict__ mlp1_b,
    u16* __restrict__ H1, u16* __restrict__ H2, u16* __restrict__ T,
    const int* __restrict__ rA, const int* __restrict__ cA, const float* __restrict__ vA,
    const int* __restrict__ rB, const int* __restrict__ cB, const float* __restrict__ vB,
    int* __restrict__ curA, int2* __restrict__ edgeA,
    int* __restrict__ curB, int2* __restrict__ edgeB) {
  __shared__ u16 As[TM * TK];
  __shared__ u16 Bs[TN * TK];

  const int b = blockIdx.x;
  const int u = b >> 4;
  const int r = b & 15;

  if (r >= 8) {
    // ---- GEMM slot ----
    const int gid = u * 8 + (r - 8);
    if (gid >= GEMM_BLKS) return;
    const int tid = threadIdx.x;
    const int lane = tid & 63;
    const int w = tid >> 6;
    const int n0 = (gid % 6) * TN;
    const int m0 = (gid / 6) * TM;
    const int wm = w >> 1, wn = w & 1;

    f32x4 acc[4][4] = {};

    const int r_l = lane >> 2;
    const int kcp = lane & 3;
    const int r16 = lane & 15;
    const int kcl = lane >> 4;

    for (int k0 = 0; k0 < DIN; k0 += TK) {
#pragma unroll
      for (int q = 0; q < 2; ++q) {
        int row = w * 32 + q * 16 + r_l;
        int kc = kcp ^ ((row >> 1) & 3);
        int gr = m0 + row; if (gr >= NN) gr = NN - 1;
        gload16(Xb + (size_t)gr * DIN + k0 + kc * 8, &As[(w * 32 + q * 16) * TK]);
        gload16(Wt + (size_t)(n0 + row) * DIN + k0 + kc * 8, &Bs[(w * 32 + q * 16) * TK]);
      }
      __syncthreads();

      short8 aF[4], bF[4];
#pragma unroll
      for (int i = 0; i < 4; ++i) {
        int m = wm * 64 + i * 16 + r16;
        aF[i] = *reinterpret_cast<const short8*>(&As[m * TK + (kcl ^ ((m >> 1) & 3)) * 8]);
        int n = wn * 64 + i * 16 + r16;
        bF[i] = *reinterpret_cast<const short8*>(&Bs[n * TK + (kcl ^ ((n >> 1) & 3)) * 8]);
      }
#pragma unroll
      for (int i = 0; i < 4; ++i)
#pragma unroll
        for (int j = 0; j < 4; ++j)
          acc[i][j] = __builtin_amdgcn_mfma_f32_16x16x32_bf16(aF[i], bF[j], acc[i][j], 0, 0, 0);
      __syncthreads();
    }

    const int bsel = n0 >> 8;
    u16* O = (bsel == 0) ? H1 : (bsel == 1) ? H2 : T;
    const int act = (bsel == 2);
    const int cb = n0 & 255;
    const int rq = lane >> 4;
#pragma unroll
    for (int i = 0; i < 4; ++i) {
#pragma unroll
      for (int rr = 0; rr < 4; ++rr) {
        int grow = m0 + wm * 64 + i * 16 + rq * 4 + rr;
        if (grow >= NN) continue;
#pragma unroll
        for (int j = 0; j < 4; ++j) {
          int c = cb + wn * 64 + j * 16 + r16;
          float v = acc[i][j][rr];
          if (act) v = tanhf(v + mlp1_b[c]);
          O[(size_t)grow * NH + c] = f2bf(v);
        }
      }
    }
  } else {
    // ---- scatter block: chunk u, slice r (r == blockIdx%8 -> same XCD per slice) ----
    const int slice = r;
    const int base = u * CHUNK;
    for (int t = threadIdx.x; t < CHUNK; t += 256) {
      int e = base + t;
      if (e < EE) {
        int rw = rA[e];
        if ((rw & 7) == slice) {
          int p = atomicAdd(&curA[rw], 1);
          int2 o; o.x = cA[e]; o.y = __float_as_int(vA[e]);
          edgeA[p] = o;
        }
      } else if (e < 2 * EE) {
        int e2 = e - EE;
        int rw = rB[e2];
        if ((rw & 7) == slice) {
          int p = atomicAdd(&curB[rw], 1);
          int2 o; o.x = cB[e2]; o.y = __float_as_int(vB[e2]);
          edgeB[p] = o;
        }
      }
    }
  }
}

// ---------------- fused SpMM(A)+SpMM(B)+attention+layer-2 GEMV ----------------
// 1 wave = 1 node. 4-deep 16 B gather pipeline per CSR; r1/r2 stay fp32 in regs.
__global__ __launch_bounds__(256) void spmm_fuse(
    const int* __restrict__ rsA, const int2* __restrict__ edgeA,
    const u16* __restrict__ H1, const float* __restrict__ b1,
    const int* __restrict__ rsB, const int2* __restrict__ edgeB,
    const u16* __restrict__ H2, const float* __restrict__ b2,
    const u16* __restrict__ T, const float* __restrict__ afw,
    const float* __restrict__ W2r1, const float* __restrict__ W2r2,
    const float* __restrict__ mlpW, const float* __restrict__ mlpb,
    float* __restrict__ Z1, float* __restrict__ Z2, float* __restrict__ Y1) {
  __shared__ float w[DIN * 3];
  __shared__ float w1[NH * 2], w2[NH * 2], wmm[NH * 2];
  int tid = threadIdx.x;
  for (int i = tid; i < DIN * 3; i += 256) w[i] = afw[i];
  for (int i = tid; i < NH * 2; i += 256) { w1[i] = W2r1[i]; w2[i] = W2r2[i]; wmm[i] = mlpW[i]; }
  __syncthreads();

  int lane = tid & 63, wv = tid >> 6;
  int n = blockIdx.x * 4 + wv;
  int h0 = (lane & 31) * 8;
  int eg = lane >> 5;

  float ac1[8] = {}, ac2[8] = {};
  // CSR-A gather
  {
    int s = rsA[n], e = rsA[n + 1];
    int i = s + eg;
    for (; i + 6 < e; i += 8) {
      int2 e0 = edgeA[i], e1 = edgeA[i + 2], e2 = edgeA[i + 4], e3 = edgeA[i + 6];
      short8 v0 = *reinterpret_cast<const short8*>(H1 + (size_t)e0.x * NH + h0);
      short8 v1 = *reinterpret_cast<const short8*>(H1 + (size_t)e1.x * NH + h0);
      short8 v2 = *reinterpret_cast<const short8*>(H1 + (size_t)e2.x * NH + h0);
      short8 v3 = *reinterpret_cast<const short8*>(H1 + (size_t)e3.x * NH + h0);
      float f0 = __int_as_float(e0.y), f1 = __int_as_float(e1.y);
      float f2 = __int_as_float(e2.y), f3 = __int_as_float(e3.y);
#pragma unroll
      for (int j = 0; j < 8; ++j)
        ac1[j] += f0 * bf2f((u16)v0[j]) + f1 * bf2f((u16)v1[j])
                + f2 * bf2f((u16)v2[j]) + f3 * bf2f((u16)v3[j]);
    }
    for (; i < e; i += 2) {
      int2 e0 = edgeA[i];
      short8 v0 = *reinterpret_cast<const short8*>(H1 + (size_t)e0.x * NH + h0);
      float f0 = __int_as_float(e0.y);
#pragma unroll
      for (int j = 0; j < 8; ++j) ac1[j] += f0 * bf2f((u16)v0[j]);
    }
  }
  // CSR-B gather
  {
    int s = rsB[n], e = rsB[n + 1];
    int i = s + eg;
    for (; i + 6 < e; i += 8) {
      int2 e0 = edgeB[i], e1 = edgeB[i + 2], e2 = edgeB[i + 4], e3 = edgeB[i + 6];
      short8 v0 = *reinterpret_cast<const short8*>(H2 + (size_t)e0.x * NH + h0);
      short8 v1 = *reinterpret_cast<const short8*>(H2 + (size_t)e1.x * NH + h0);
      short8 v2 = *reinterpret_cast<const short8*>(H2 + (size_t)e2.x * NH + h0);
      short8 v3 = *reinterpret_cast<const short8*>(H2 + (size_t)e3.x * NH + h0);
      float f0 = __int_as_float(e0.y), f1 = __int_as_float(e1.y);
      float f2 = __int_as_float(e2.y), f3 = __int_as_float(e3.y);
#pragma unroll
      for (int j = 0; j < 8; ++j)
        ac2[j] += f0 * bf2f((u16)v0[j]) + f1 * bf2f((u16)v1[j])
                + f2 * bf2f((u16)v2[j]) + f3 * bf2f((u16)v3[j]);
    }
    for (; i < e; i += 2) {
      int2 e0 = edgeB[i];
      short8 v0 = *reinterpret_cast<const short8*>(H2 + (size_t)e0.x * NH + h0);
      float f0 = __int_as_float(e0.y);
#pragma unroll
      for (int j = 0; j < 8; ++j) ac2[j] += f0 * bf2f((u16)v0[j]);
    }
  }
  // combine the two edge groups -> all 64 lanes hold full sums for their h-chunk
#pragma unroll
  for (int j = 0; j < 8; ++j) {
    ac1[j] += __shfl_xor(ac1[j], 32, 64);
    ac2[j] += __shfl_xor(ac2[j], 32, 64);
  }

  // + bias, T row
  float r1[8], r2[8], t8[8];
  {
    float4 bA0 = *reinterpret_cast<const float4*>(b1 + h0);
    float4 bA1 = *reinterpret_cast<const float4*>(b1 + h0 + 4);
    float4 bB0 = *reinterpret_cast<const float4*>(b2 + h0);
    float4 bB1 = *reinterpret_cast<const float4*>(b2 + h0 + 4);
    float bbA[8] = {bA0.x, bA0.y, bA0.z, bA0.w, bA1.x, bA1.y, bA1.z, bA1.w};
    float bbB[8] = {bB0.x, bB0.y, bB0.z, bB0.w, bB1.x, bB1.y, bB1.z, bB1.w};
    short8 tv = *reinterpret_cast<const short8*>(T + (size_t)n * NH + h0);
#pragma unroll
    for (int j = 0; j < 8; ++j) {
      r1[j] = ac1[j] + bbA[j];
      r2[j] = ac2[j] + bbB[j];
      t8[j] = bf2f((u16)tv[j]);
    }
  }

  // attention logits (each 32-lane half independently sums all 32 h-chunks)
  float l0 = 0.f, l1 = 0.f, l2 = 0.f;
#pragma unroll
  for (int k = 0; k < 8; ++k) {
    int h = h0 + k;
    l0 += r1[k] * w[h * 3 + 0] + r2[k] * w[(NH + h) * 3 + 0] + t8[k] * w[(2 * NH + h) * 3 + 0];
    l1 += r1[k] * w[h * 3 + 1] + r2[k] * w[(NH + h) * 3 + 1] + t8[k] * w[(2 * NH + h) * 3 + 1];
    l2 += r1[k] * w[h * 3 + 2] + r2[k] * w[(NH + h) * 3 + 2] + t8[k] * w[(2 * NH + h) * 3 + 2];
  }
#pragma unroll
  for (int off = 16; off > 0; off >>= 1) {
    l0 += __shfl_xor(l0, off, 64);
    l1 += __shfl_xor(l1, off, 64);
    l2 += __shfl_xor(l2, off, 64);
  }
  l0 = fabsf(l0); l1 = fabsf(l1); l2 = fabsf(l2);
  float mx = fmaxf(l0, fmaxf(l1, l2));
  float e0 = expf(l0 - mx), e1 = expf(l1 - mx), e2 = expf(l2 - mx);
  float inv = 1.f / (e0 + e1 + e2);
  float s0 = e0 * inv, s1 = e1 * inv, s2 = e2 * inv;

  // layer-2 GEMV on in-register x1
  float p10 = 0.f, p11 = 0.f, p20 = 0.f, p21 = 0.f, p30 = 0.f, p31 = 0.f;
#pragma unroll
  for (int k = 0; k < 8; ++k) {
    int h = h0 + k;
    float xv = s0 * r1[k] + s1 * r2[k] + s2 * t8[k];
    p10 += xv * w1[h * 2 + 0]; p11 += xv * w1[h * 2 + 1];
    p20 += xv * w2[h * 2 + 0]; p21 += xv * w2[h * 2 + 1];
    p30 += xv * wmm[h * 2 + 0]; p31 += xv * wmm[h * 2 + 1];
  }
#pragma unroll
  for (int off = 16; off > 0; off >>= 1) {
    p10 += __shfl_xor(p10, off, 64); p11 += __shfl_xor(p11, off, 64);
    p20 += __shfl_xor(p20, off, 64); p21 += __shfl_xor(p21, off, 64);
    p30 += __shfl_xor(p30, off, 64); p31 += __shfl_xor(p31, off, 64);
  }
  if (lane == 0) {
    Z1[n * 2 + 0] = p10; Z1[n * 2 + 1] = p11;
    Z2[n * 2 + 0] = p20; Z2[n * 2 + 1] = p21;
    Y1[n * 2 + 0] = tanhf(p30 + mlpb[0]);
    Y1[n * 2 + 1] = tanhf(p31 + mlpb[1]);
  }
}

// ---------------- layer-2 SpMM (2 cols) + final sum ----------------
__global__ __launch_bounds__(256) void spmm2_final(
    const int* __restrict__ rsA, const int2* __restrict__ edgeA,
    const int* __restrict__ rsB, const int2* __restrict__ edgeB,
    const float* __restrict__ Z1, const float* __restrict__ Z2, const float* __restrict__ Y1,
    const float* __restrict__ b2r1, const float* __restrict__ b2r2,
    float* __restrict__ out) {
  int tid = threadIdx.x;
  int lane = tid & 63, wave = tid >> 6;
  int n = blockIdx.x * 4 + wave;
  float a0 = 0.f, a1 = 0.f;
  {
    int s = rsA[n], e = rsA[n + 1];
    for (int i = s + lane; i < e; i += 64) {
      int2 ed = edgeA[i];
      float v = __int_as_float(ed.y);
      float2 z = *reinterpret_cast<const float2*>(Z1 + ed.x * 2);
      a0 += v * z.x; a1 += v * z.y;
    }
  }
  float c0 = 0.f, c1 = 0.f;
  {
    int s = rsB[n], e = rsB[n + 1];
    for (int i = s + lane; i < e; i += 64) {
      int2 ed = edgeB[i];
      float v = __int_as_float(ed.y);
      float2 z = *reinterpret_cast<const float2*>(Z2 + ed.x * 2);
      c0 += v * z.x; c1 += v * z.y;
    }
  }
#pragma unroll
  for (int off = 32; off > 0; off >>= 1) {
    a0 += __shfl_down(a0, off, 64); a1 += __shfl_down(a1, off, 64);
    c0 += __shfl_down(c0, off, 64); c1 += __shfl_down(c1, off, 64);
  }
  if (lane == 0) {
    out[n * 2 + 0] = (a0 + b2r1[0]) + (c0 + b2r2[0]) + Y1[n * 2 + 0];
    out[n * 2 + 1] = (a1 + b2r1[1]) + (c1 + b2r2[1]) + Y1[n * 2 + 1];
  }
}

extern "C" void kernel_launch(void* const* d_in, const int* in_sizes, int n_in,
                              void* d_out, int out_size, void* d_ws, size_t ws_size,
                              hipStream_t stream) {
  const float* x        = (const float*)d_in[0];
  const int*   adj_rows = (const int*)d_in[1];
  const int*   adj_cols = (const int*)d_in[2];
  const float* adj_vals = (const float*)d_in[3];
  const int*   s_rows   = (const int*)d_in[4];
  const int*   s_cols   = (const int*)d_in[5];
  const float* s_vals   = (const float*)d_in[6];
  const float* W1r1     = (const float*)d_in[7];
  const float* b1r1     = (const float*)d_in[8];
  const float* W1r2     = (const float*)d_in[9];
  const float* b1r2     = (const float*)d_in[10];
  const float* mlp1_W   = (const float*)d_in[11];
  const float* mlp1_b   = (const float*)d_in[12];
  const float* af1_w    = (const float*)d_in[13];
  const float* W2r1     = (const float*)d_in[14];
  const float* b2r1     = (const float*)d_in[15];
  const float* W2r2     = (const float*)d_in[16];
  const float* b2r2     = (const float*)d_in[17];
  const float* mlp2_W   = (const float*)d_in[18];
  const float* mlp2_b   = (const float*)d_in[19];
  float* out = (float*)d_out;

  char* p = (char*)d_ws;
  auto alloc = [&](size_t b) { char* r = p; p += (b + 255) & ~(size_t)255; return r; };

  // Xb region (76.8 MB) is dead after gemm; Z1/Z2/Y1 alias into it.
  char* xb_region = alloc((size_t)NN * DIN * 2);
  u16* Xb = (u16*)xb_region;
  float* Z1 = (float*)xb_region;
  float* Z2 = (float*)(xb_region + (size_t)NN * 2 * 4);
  float* Y1 = (float*)(xb_region + (size_t)NN * 4 * 4);

  u16* H1 = (u16*)alloc((size_t)NN * NH * 2);
  u16* H2 = (u16*)alloc((size_t)NN * NH * 2);
  u16* T  = (u16*)alloc((size_t)NN * NH * 2);
  u16* Wt = (u16*)alloc((size_t)DIN * DIN * 2);
  int*  rsA   = (int*)alloc((size_t)(NN + 1) * 4);
  int*  curA  = (int*)alloc((size_t)NN * 4);
  int2* edgeA = (int2*)alloc((size_t)EE * 8);
  int*  rsB   = (int*)alloc((size_t)(NN + 1) * 4);
  int*  curB  = (int*)alloc((size_t)NN * 4);
  int2* edgeB = (int2*)alloc((size_t)EE * 8);
  int*  bsum  = (int*)alloc(2 * 98 * 4);

  // counters zero + fused prep (convert_x | hist | pack_wt)
  hipMemsetAsync(curA, 0, (size_t)NN * 4, stream);
  hipMemsetAsync(curB, 0, (size_t)NN * 4, stream);
  prep_kernel<<<52304, 256, 0, stream>>>(x, Xb, adj_rows, s_rows, curA, curB,
                                         W1r1, W1r2, mlp1_W, Wt);

  // 3-phase scan -> rs + exclusive cursors (both CSRs)
  dim3 gsc(98, 2);
  scan1<<<gsc, 256, 0, stream>>>(curA, rsA, curB, rsB, bsum);
  scan2<<<dim3(1, 2), 128, 0, stream>>>(bsum);
  scan3<<<gsc, 512, 0, stream>>>(curA, rsA, curB, rsB, bsum);

  // fused layer-1 GEMM + slice-partitioned CSR scatter
  gemm_scatter<<<TOT_BLKS, 256, 0, stream>>>(Xb, Wt, mlp1_b, H1, H2, T,
                                             adj_rows, adj_cols, adj_vals,
                                             s_rows, s_cols, s_vals,
                                             curA, edgeA, curB, edgeB);

  // fused SpMM(A)+SpMM(B)+attention+layer-2 GEMV (Z/Y overwrite dead Xb region)
  spmm_fuse<<<NN / 4, 256, 0, stream>>>(rsA, edgeA, H1, b1r1,
                                        rsB, edgeB, H2, b1r2,
                                        T, af1_w, W2r1, W2r2, mlp2_W, mlp2_b,
                                        Z1, Z2, Y1);

  // layer-2 SpMMs + final sum
  spmm2_final<<<NN / 4, 256, 0, stream>>>(rsA, edgeA, rsB, edgeB,
                                          Z1, Z2, Y1, b2r1, b2r2, out);
}

// Round 6
// 905.628 us; speedup vs baseline: 1.2946x; 1.2946x over previous
//
#include <hip/hip_runtime.h>
#include <hip/hip_bf16.h>

#define NN 50000
#define EE 1600000
#define DIN 768
#define NH 256

typedef unsigned short u16;
typedef unsigned int u32;

typedef __attribute__((ext_vector_type(8))) short short8;
typedef __attribute__((ext_vector_type(4))) float f32x4;

__device__ __forceinline__ float bf2f(u16 u) {
  union { u32 i; float f; } x; x.i = ((u32)u) << 16; return x.f;
}
__device__ __forceinline__ u16 f2bf(float f) {
  union { float f; u32 u; } x; x.f = f;
  u32 r = x.u + 0x7fff + ((x.u >> 16) & 1);  // RNE
  return (u16)(r >> 16);
}

// ---------------- fused prep: convert_x + hist + pack_wt ----------------
__global__ __launch_bounds__(256) void prep_kernel(
    const float* __restrict__ X, u16* __restrict__ Xb,
    const int* __restrict__ rA, const int* __restrict__ rB,
    int* __restrict__ cntA, int* __restrict__ cntB,
    const float* __restrict__ Wa, const float* __restrict__ Wb,
    const float* __restrict__ Wc, u16* __restrict__ Wt) {
  int b = blockIdx.x;
  if (b < 37500) {
    size_t idx = (size_t)b * 256 + threadIdx.x;
    float4 v = reinterpret_cast<const float4*>(X)[idx];
    ushort4 o;
    o.x = f2bf(v.x); o.y = f2bf(v.y); o.z = f2bf(v.z); o.w = f2bf(v.w);
    reinterpret_cast<ushort4*>(Xb)[idx] = o;
  } else if (b < 50000) {
    int e = (b - 37500) * 256 + threadIdx.x;
    if (e < EE) atomicAdd(&cntA[rA[e]], 1);
    else        atomicAdd(&cntB[rB[e - EE]], 1);
  } else {
    int idx = (b - 50000) * 256 + threadIdx.x;
    int n = idx / DIN, k = idx - n * DIN;
    const float* W = (n < 256) ? Wa : (n < 512) ? Wb : Wc;
    Wt[idx] = f2bf(W[(size_t)k * NH + (n & 255)]);
  }
}

// ---------------- 3-phase scan (both CSRs via blockIdx.y) ----------------
__global__ __launch_bounds__(256) void scan1(int* __restrict__ cntA, int* __restrict__ rsA,
                                             int* __restrict__ cntB, int* __restrict__ rsB,
                                             int* __restrict__ bsum) {
  int* cnt = (blockIdx.y == 0) ? cntA : cntB;
  int* rs  = (blockIdx.y == 0) ? rsA  : rsB;
  int* bs  = bsum + blockIdx.y * 98;
  __shared__ int wsum[4];
  int t = threadIdx.x, lane = t & 63, wid = t >> 6;
  int i0 = blockIdx.x * 512 + 2 * t;
  int v0 = (i0 < NN) ? cnt[i0] : 0;
  int v1 = (i0 + 1 < NN) ? cnt[i0 + 1] : 0;
  int s = v0 + v1;
  int sc = s;
#pragma unroll
  for (int off = 1; off < 64; off <<= 1) {
    int tv = __shfl_up(sc, off, 64);
    if (lane >= off) sc += tv;
  }
  if (lane == 63) wsum[wid] = sc;
  __syncthreads();
  int woff = 0;
  for (int w = 0; w < wid; ++w) woff += wsum[w];
  int excl = woff + sc - s;
  if (i0 < NN)     { cnt[i0] = excl;          rs[i0 + 1] = excl + v0; }
  if (i0 + 1 < NN) { cnt[i0 + 1] = excl + v0; rs[i0 + 2] = excl + v0 + v1; }
  if (t == 255) bs[blockIdx.x] = woff + sc;
  if (blockIdx.x == 0 && t == 0) rs[0] = 0;
}

__global__ __launch_bounds__(128) void scan2(int* __restrict__ bsum) {
  int* bs = bsum + blockIdx.y * 98;
  __shared__ int tmp[128];
  int t = threadIdx.x;
  int orig = (t < 98) ? bs[t] : 0;
  tmp[t] = orig;
  __syncthreads();
  for (int off = 1; off < 128; off <<= 1) {
    int v = (t >= off) ? tmp[t - off] : 0;
    __syncthreads();
    tmp[t] += v;
    __syncthreads();
  }
  if (t < 98) bs[t] = tmp[t] - orig;
}

__global__ __launch_bounds__(512) void scan3(int* __restrict__ cntA, int* __restrict__ rsA,
                                             int* __restrict__ cntB, int* __restrict__ rsB,
                                             const int* __restrict__ bsum) {
  int* cnt = (blockIdx.y == 0) ? cntA : cntB;
  int* rs  = (blockIdx.y == 0) ? rsA  : rsB;
  int off = bsum[blockIdx.y * 98 + blockIdx.x];
  int i = blockIdx.x * 512 + threadIdx.x;
  if (i < NN) { cnt[i] += off; rs[i + 1] += off; }
}

// ---------------- fused layer-1 MFMA GEMM + CSR scatter (packed u32 edges) ----------------
#define TM 128
#define TN 128
#define TK 32
#define GEMM_BLKS 2346           // 6 * 391
#define TOT_BLKS (GEMM_BLKS + 12500)

__device__ __forceinline__ void gload16(const u16* g, u16* lds) {
  __builtin_amdgcn_global_load_lds((const __attribute__((address_space(1))) unsigned int*)g,
                                   (__attribute__((address_space(3))) unsigned int*)lds, 16, 0, 0);
}

__global__ __launch_bounds__(256) void gemm_scatter(
    const u16* __restrict__ Xb, const u16* __restrict__ Wt, const float* __restrict__ mlp1_b,
    u16* __restrict__ H1, u16* __restrict__ H2, u16* __restrict__ T,
    const int* __restrict__ rA, const int* __restrict__ cA, const float* __restrict__ vA,
    const int* __restrict__ rB, const int* __restrict__ cB, const float* __restrict__ vB,
    int* __restrict__ curA, u32* __restrict__ edgeA,
    int* __restrict__ curB, u32* __restrict__ edgeB) {
  __shared__ u16 As[TM * TK];
  __shared__ u16 Bs[TN * TK];

  const int b = blockIdx.x;
  // interleave: exactly GEMM_BLKS gemm blocks spread evenly over TOT_BLKS
  const int lo = (b * GEMM_BLKS) / TOT_BLKS;
  const int hi = ((b + 1) * GEMM_BLKS) / TOT_BLKS;

  if (hi > lo) {
    // ---- GEMM block ----
    const int gid = lo;
    const int tid = threadIdx.x;
    const int lane = tid & 63;
    const int w = tid >> 6;
    const int n0 = (gid % 6) * TN;
    const int m0 = (gid / 6) * TM;
    const int wm = w >> 1, wn = w & 1;

    f32x4 acc[4][4] = {};

    const int r_l = lane >> 2;
    const int kcp = lane & 3;
    const int r16 = lane & 15;
    const int kcl = lane >> 4;

    for (int k0 = 0; k0 < DIN; k0 += TK) {
#pragma unroll
      for (int q = 0; q < 2; ++q) {
        int row = w * 32 + q * 16 + r_l;
        int kc = kcp ^ ((row >> 1) & 3);
        int gr = m0 + row; if (gr >= NN) gr = NN - 1;
        gload16(Xb + (size_t)gr * DIN + k0 + kc * 8, &As[(w * 32 + q * 16) * TK]);
        gload16(Wt + (size_t)(n0 + row) * DIN + k0 + kc * 8, &Bs[(w * 32 + q * 16) * TK]);
      }
      __syncthreads();

      short8 aF[4], bF[4];
#pragma unroll
      for (int i = 0; i < 4; ++i) {
        int m = wm * 64 + i * 16 + r16;
        aF[i] = *reinterpret_cast<const short8*>(&As[m * TK + (kcl ^ ((m >> 1) & 3)) * 8]);
        int n = wn * 64 + i * 16 + r16;
        bF[i] = *reinterpret_cast<const short8*>(&Bs[n * TK + (kcl ^ ((n >> 1) & 3)) * 8]);
      }
#pragma unroll
      for (int i = 0; i < 4; ++i)
#pragma unroll
        for (int j = 0; j < 4; ++j)
          acc[i][j] = __builtin_amdgcn_mfma_f32_16x16x32_bf16(aF[i], bF[j], acc[i][j], 0, 0, 0);
      __syncthreads();
    }

    const int bsel = n0 >> 8;
    u16* O = (bsel == 0) ? H1 : (bsel == 1) ? H2 : T;
    const int act = (bsel == 2);
    const int cb = n0 & 255;
    const int rq = lane >> 4;
#pragma unroll
    for (int i = 0; i < 4; ++i) {
#pragma unroll
      for (int rr = 0; rr < 4; ++rr) {
        int grow = m0 + wm * 64 + i * 16 + rq * 4 + rr;
        if (grow >= NN) continue;
#pragma unroll
        for (int j = 0; j < 4; ++j) {
          int c = cb + wn * 64 + j * 16 + r16;
          float v = acc[i][j][rr];
          if (act) v = tanhf(v + mlp1_b[c]);
          O[(size_t)grow * NH + c] = f2bf(v);
        }
      }
    }
  } else {
    // ---- scatter block: 1 edge per thread, packed u32 (col:16 | bf16val:16) ----
    const int sid = b - lo;
    int e = sid * 256 + threadIdx.x;
    if (e < EE) {
      int r = rA[e];
      int p = atomicAdd(&curA[r], 1);
      edgeA[p] = (u32)(u16)cA[e] | ((u32)f2bf(vA[e]) << 16);
    } else {
      e -= EE;
      int r = rB[e];
      int p = atomicAdd(&curB[r], 1);
      edgeB[p] = (u32)(u16)cB[e] | ((u32)f2bf(vB[e]) << 16);
    }
  }
}

// ---------------- fused SpMM(A)+SpMM(B)+attention+layer-2 GEMV ----------------
// 1 wave = 1 node. 4-deep 16 B gather pipeline per CSR; r1/r2 stay fp32 in regs.
__global__ __launch_bounds__(256) void spmm_fuse(
    const int* __restrict__ rsA, const u32* __restrict__ edgeA,
    const u16* __restrict__ H1, const float* __restrict__ b1,
    const int* __restrict__ rsB, const u32* __restrict__ edgeB,
    const u16* __restrict__ H2, const float* __restrict__ b2,
    const u16* __restrict__ T, const float* __restrict__ afw,
    const float* __restrict__ W2r1, const float* __restrict__ W2r2,
    const float* __restrict__ mlpW, const float* __restrict__ mlpb,
    float* __restrict__ Z1, float* __restrict__ Z2, float* __restrict__ Y1) {
  __shared__ float w[DIN * 3];
  __shared__ float w1[NH * 2], w2[NH * 2], wmm[NH * 2];
  int tid = threadIdx.x;
  for (int i = tid; i < DIN * 3; i += 256) w[i] = afw[i];
  for (int i = tid; i < NH * 2; i += 256) { w1[i] = W2r1[i]; w2[i] = W2r2[i]; wmm[i] = mlpW[i]; }
  __syncthreads();

  int lane = tid & 63, wv = tid >> 6;
  int n = blockIdx.x * 4 + wv;
  int h0 = (lane & 31) * 8;
  int eg = lane >> 5;

  float ac1[8] = {}, ac2[8] = {};
  // CSR-A gather
  {
    int s = rsA[n], e = rsA[n + 1];
    int i = s + eg;
    for (; i + 6 < e; i += 8) {
      u32 e0 = edgeA[i], e1 = edgeA[i + 2], e2 = edgeA[i + 4], e3 = edgeA[i + 6];
      short8 v0 = *reinterpret_cast<const short8*>(H1 + (size_t)(e0 & 0xFFFF) * NH + h0);
      short8 v1 = *reinterpret_cast<const short8*>(H1 + (size_t)(e1 & 0xFFFF) * NH + h0);
      short8 v2 = *reinterpret_cast<const short8*>(H1 + (size_t)(e2 & 0xFFFF) * NH + h0);
      short8 v3 = *reinterpret_cast<const short8*>(H1 + (size_t)(e3 & 0xFFFF) * NH + h0);
      float f0 = bf2f((u16)(e0 >> 16)), f1 = bf2f((u16)(e1 >> 16));
      float f2 = bf2f((u16)(e2 >> 16)), f3 = bf2f((u16)(e3 >> 16));
#pragma unroll
      for (int j = 0; j < 8; ++j)
        ac1[j] += f0 * bf2f((u16)v0[j]) + f1 * bf2f((u16)v1[j])
                + f2 * bf2f((u16)v2[j]) + f3 * bf2f((u16)v3[j]);
    }
    for (; i < e; i += 2) {
      u32 e0 = edgeA[i];
      short8 v0 = *reinterpret_cast<const short8*>(H1 + (size_t)(e0 & 0xFFFF) * NH + h0);
      float f0 = bf2f((u16)(e0 >> 16));
#pragma unroll
      for (int j = 0; j < 8; ++j) ac1[j] += f0 * bf2f((u16)v0[j]);
    }
  }
  // CSR-B gather
  {
    int s = rsB[n], e = rsB[n + 1];
    int i = s + eg;
    for (; i + 6 < e; i += 8) {
      u32 e0 = edgeB[i], e1 = edgeB[i + 2], e2 = edgeB[i + 4], e3 = edgeB[i + 6];
      short8 v0 = *reinterpret_cast<const short8*>(H2 + (size_t)(e0 & 0xFFFF) * NH + h0);
      short8 v1 = *reinterpret_cast<const short8*>(H2 + (size_t)(e1 & 0xFFFF) * NH + h0);
      short8 v2 = *reinterpret_cast<const short8*>(H2 + (size_t)(e2 & 0xFFFF) * NH + h0);
      short8 v3 = *reinterpret_cast<const short8*>(H2 + (size_t)(e3 & 0xFFFF) * NH + h0);
      float f0 = bf2f((u16)(e0 >> 16)), f1 = bf2f((u16)(e1 >> 16));
      float f2 = bf2f((u16)(e2 >> 16)), f3 = bf2f((u16)(e3 >> 16));
#pragma unroll
      for (int j = 0; j < 8; ++j)
        ac2[j] += f0 * bf2f((u16)v0[j]) + f1 * bf2f((u16)v1[j])
                + f2 * bf2f((u16)v2[j]) + f3 * bf2f((u16)v3[j]);
    }
    for (; i < e; i += 2) {
      u32 e0 = edgeB[i];
      short8 v0 = *reinterpret_cast<const short8*>(H2 + (size_t)(e0 & 0xFFFF) * NH + h0);
      float f0 = bf2f((u16)(e0 >> 16));
#pragma unroll
      for (int j = 0; j < 8; ++j) ac2[j] += f0 * bf2f((u16)v0[j]);
    }
  }
#pragma unroll
  for (int j = 0; j < 8; ++j) {
    ac1[j] += __shfl_xor(ac1[j], 32, 64);
    ac2[j] += __shfl_xor(ac2[j], 32, 64);
  }

  // + bias, T row
  float r1[8], r2[8], t8[8];
  {
    float4 bA0 = *reinterpret_cast<const float4*>(b1 + h0);
    float4 bA1 = *reinterpret_cast<const float4*>(b1 + h0 + 4);
    float4 bB0 = *reinterpret_cast<const float4*>(b2 + h0);
    float4 bB1 = *reinterpret_cast<const float4*>(b2 + h0 + 4);
    float bbA[8] = {bA0.x, bA0.y, bA0.z, bA0.w, bA1.x, bA1.y, bA1.z, bA1.w};
    float bbB[8] = {bB0.x, bB0.y, bB0.z, bB0.w, bB1.x, bB1.y, bB1.z, bB1.w};
    short8 tv = *reinterpret_cast<const short8*>(T + (size_t)n * NH + h0);
#pragma unroll
    for (int j = 0; j < 8; ++j) {
      r1[j] = ac1[j] + bbA[j];
      r2[j] = ac2[j] + bbB[j];
      t8[j] = bf2f((u16)tv[j]);
    }
  }

  // attention logits
  float l0 = 0.f, l1 = 0.f, l2 = 0.f;
#pragma unroll
  for (int k = 0; k < 8; ++k) {
    int h = h0 + k;
    l0 += r1[k] * w[h * 3 + 0] + r2[k] * w[(NH + h) * 3 + 0] + t8[k] * w[(2 * NH + h) * 3 + 0];
    l1 += r1[k] * w[h * 3 + 1] + r2[k] * w[(NH + h) * 3 + 1] + t8[k] * w[(2 * NH + h) * 3 + 1];
    l2 += r1[k] * w[h * 3 + 2] + r2[k] * w[(NH + h) * 3 + 2] + t8[k] * w[(2 * NH + h) * 3 + 2];
  }
#pragma unroll
  for (int off = 16; off > 0; off >>= 1) {
    l0 += __shfl_xor(l0, off, 64);
    l1 += __shfl_xor(l1, off, 64);
    l2 += __shfl_xor(l2, off, 64);
  }
  l0 = fabsf(l0); l1 = fabsf(l1); l2 = fabsf(l2);
  float mx = fmaxf(l0, fmaxf(l1, l2));
  float e0 = expf(l0 - mx), e1 = expf(l1 - mx), e2 = expf(l2 - mx);
  float inv = 1.f / (e0 + e1 + e2);
  float s0 = e0 * inv, s1 = e1 * inv, s2 = e2 * inv;

  // layer-2 GEMV on in-register x1
  float p10 = 0.f, p11 = 0.f, p20 = 0.f, p21 = 0.f, p30 = 0.f, p31 = 0.f;
#pragma unroll
  for (int k = 0; k < 8; ++k) {
    int h = h0 + k;
    float xv = s0 * r1[k] + s1 * r2[k] + s2 * t8[k];
    p10 += xv * w1[h * 2 + 0]; p11 += xv * w1[h * 2 + 1];
    p20 += xv * w2[h * 2 + 0]; p21 += xv * w2[h * 2 + 1];
    p30 += xv * wmm[h * 2 + 0]; p31 += xv * wmm[h * 2 + 1];
  }
#pragma unroll
  for (int off = 16; off > 0; off >>= 1) {
    p10 += __shfl_xor(p10, off, 64); p11 += __shfl_xor(p11, off, 64);
    p20 += __shfl_xor(p20, off, 64); p21 += __shfl_xor(p21, off, 64);
    p30 += __shfl_xor(p30, off, 64); p31 += __shfl_xor(p31, off, 64);
  }
  if (lane == 0) {
    Z1[n * 2 + 0] = p10; Z1[n * 2 + 1] = p11;
    Z2[n * 2 + 0] = p20; Z2[n * 2 + 1] = p21;
    Y1[n * 2 + 0] = tanhf(p30 + mlpb[0]);
    Y1[n * 2 + 1] = tanhf(p31 + mlpb[1]);
  }
}

// ---------------- layer-2 SpMM (2 cols) + final sum ----------------
__global__ __launch_bounds__(256) void spmm2_final(
    const int* __restrict__ rsA, const u32* __restrict__ edgeA,
    const int* __restrict__ rsB, const u32* __restrict__ edgeB,
    const float* __restrict__ Z1, const float* __restrict__ Z2, const float* __restrict__ Y1,
    const float* __restrict__ b2r1, const float* __restrict__ b2r2,
    float* __restrict__ out) {
  int tid = threadIdx.x;
  int lane = tid & 63, wave = tid >> 6;
  int n = blockIdx.x * 4 + wave;
  float a0 = 0.f, a1 = 0.f;
  {
    int s = rsA[n], e = rsA[n + 1];
    for (int i = s + lane; i < e; i += 64) {
      u32 ed = edgeA[i];
      float v = bf2f((u16)(ed >> 16));
      float2 z = *reinterpret_cast<const float2*>(Z1 + (ed & 0xFFFF) * 2);
      a0 += v * z.x; a1 += v * z.y;
    }
  }
  float c0 = 0.f, c1 = 0.f;
  {
    int s = rsB[n], e = rsB[n + 1];
    for (int i = s + lane; i < e; i += 64) {
      u32 ed = edgeB[i];
      float v = bf2f((u16)(ed >> 16));
      float2 z = *reinterpret_cast<const float2*>(Z2 + (ed & 0xFFFF) * 2);
      c0 += v * z.x; c1 += v * z.y;
    }
  }
#pragma unroll
  for (int off = 32; off > 0; off >>= 1) {
    a0 += __shfl_down(a0, off, 64); a1 += __shfl_down(a1, off, 64);
    c0 += __shfl_down(c0, off, 64); c1 += __shfl_down(c1, off, 64);
  }
  if (lane == 0) {
    out[n * 2 + 0] = (a0 + b2r1[0]) + (c0 + b2r2[0]) + Y1[n * 2 + 0];
    out[n * 2 + 1] = (a1 + b2r1[1]) + (c1 + b2r2[1]) + Y1[n * 2 + 1];
  }
}

extern "C" void kernel_launch(void* const* d_in, const int* in_sizes, int n_in,
                              void* d_out, int out_size, void* d_ws, size_t ws_size,
                              hipStream_t stream) {
  const float* x        = (const float*)d_in[0];
  const int*   adj_rows = (const int*)d_in[1];
  const int*   adj_cols = (const int*)d_in[2];
  const float* adj_vals = (const float*)d_in[3];
  const int*   s_rows   = (const int*)d_in[4];
  const int*   s_cols   = (const int*)d_in[5];
  const float* s_vals   = (const float*)d_in[6];
  const float* W1r1     = (const float*)d_in[7];
  const float* b1r1     = (const float*)d_in[8];
  const float* W1r2     = (const float*)d_in[9];
  const float* b1r2     = (const float*)d_in[10];
  const float* mlp1_W   = (const float*)d_in[11];
  const float* mlp1_b   = (const float*)d_in[12];
  const float* af1_w    = (const float*)d_in[13];
  const float* W2r1     = (const float*)d_in[14];
  const float* b2r1     = (const float*)d_in[15];
  const float* W2r2     = (const float*)d_in[16];
  const float* b2r2     = (const float*)d_in[17];
  const float* mlp2_W   = (const float*)d_in[18];
  const float* mlp2_b   = (const float*)d_in[19];
  float* out = (float*)d_out;

  char* p = (char*)d_ws;
  auto alloc = [&](size_t b) { char* r = p; p += (b + 255) & ~(size_t)255; return r; };

  // Xb region (76.8 MB) is dead after gemm; Z1/Z2/Y1 alias into it.
  char* xb_region = alloc((size_t)NN * DIN * 2);
  u16* Xb = (u16*)xb_region;
  float* Z1 = (float*)xb_region;
  float* Z2 = (float*)(xb_region + (size_t)NN * 2 * 4);
  float* Y1 = (float*)(xb_region + (size_t)NN * 4 * 4);

  u16* H1 = (u16*)alloc((size_t)NN * NH * 2);
  u16* H2 = (u16*)alloc((size_t)NN * NH * 2);
  u16* T  = (u16*)alloc((size_t)NN * NH * 2);
  u16* Wt = (u16*)alloc((size_t)DIN * DIN * 2);
  int* rsA   = (int*)alloc((size_t)(NN + 1) * 4);
  int* curA  = (int*)alloc((size_t)NN * 4);
  u32* edgeA = (u32*)alloc((size_t)EE * 4);
  int* rsB   = (int*)alloc((size_t)(NN + 1) * 4);
  int* curB  = (int*)alloc((size_t)NN * 4);
  u32* edgeB = (u32*)alloc((size_t)EE * 4);
  int* bsum  = (int*)alloc(2 * 98 * 4);

  // counters zero + fused prep (convert_x | hist | pack_wt)
  hipMemsetAsync(curA, 0, (size_t)NN * 4, stream);
  hipMemsetAsync(curB, 0, (size_t)NN * 4, stream);
  prep_kernel<<<52304, 256, 0, stream>>>(x, Xb, adj_rows, s_rows, curA, curB,
                                         W1r1, W1r2, mlp1_W, Wt);

  // 3-phase scan -> rs + exclusive cursors (both CSRs)
  dim3 gsc(98, 2);
  scan1<<<gsc, 256, 0, stream>>>(curA, rsA, curB, rsB, bsum);
  scan2<<<dim3(1, 2), 128, 0, stream>>>(bsum);
  scan3<<<gsc, 512, 0, stream>>>(curA, rsA, curB, rsB, bsum);

  // fused layer-1 GEMM + CSR scatter (interleaved block mix, packed edges)
  gemm_scatter<<<TOT_BLKS, 256, 0, stream>>>(Xb, Wt, mlp1_b, H1, H2, T,
                                             adj_rows, adj_cols, adj_vals,
                                             s_rows, s_cols, s_vals,
                                             curA, edgeA, curB, edgeB);

  // fused SpMM(A)+SpMM(B)+attention+layer-2 GEMV (Z/Y overwrite dead Xb region)
  spmm_fuse<<<NN / 4, 256, 0, stream>>>(rsA, edgeA, H1, b1r1,
                                        rsB, edgeB, H2, b1r2,
                                        T, af1_w, W2r1, W2r2, mlp2_W, mlp2_b,
                                        Z1, Z2, Y1);

  // layer-2 SpMMs + final sum
  spmm2_final<<<NN / 4, 256, 0, stream>>>(rsA, edgeA, rsB, edgeB,
                                          Z1, Z2, Y1, b2r1, b2r2, out);
}

// Round 7
// 865.202 us; speedup vs baseline: 1.3551x; 1.0467x over previous
//
#include <hip/hip_runtime.h>
#include <hip/hip_bf16.h>

#define NN 50000
#define EE 1600000
#define DIN 768
#define NH 256

typedef unsigned short u16;
typedef unsigned int u32;

typedef __attribute__((ext_vector_type(8))) short short8;
typedef __attribute__((ext_vector_type(4))) float f32x4;

__device__ __forceinline__ float bf2f(u16 u) {
  union { u32 i; float f; } x; x.i = ((u32)u) << 16; return x.f;
}
__device__ __forceinline__ u16 f2bf(float f) {
  union { float f; u32 u; } x; x.f = f;
  u32 r = x.u + 0x7fff + ((x.u >> 16) & 1);  // RNE
  return (u16)(r >> 16);
}

// ---------------- fused prep: convert_x + hist + pack_wt ----------------
__global__ __launch_bounds__(256) void prep_kernel(
    const float* __restrict__ X, u16* __restrict__ Xb,
    const int* __restrict__ rA, const int* __restrict__ rB,
    int* __restrict__ cntA, int* __restrict__ cntB,
    const float* __restrict__ Wa, const float* __restrict__ Wb,
    const float* __restrict__ Wc, u16* __restrict__ Wt) {
  int b = blockIdx.x;
  if (b < 37500) {
    size_t idx = (size_t)b * 256 + threadIdx.x;
    float4 v = reinterpret_cast<const float4*>(X)[idx];
    ushort4 o;
    o.x = f2bf(v.x); o.y = f2bf(v.y); o.z = f2bf(v.z); o.w = f2bf(v.w);
    reinterpret_cast<ushort4*>(Xb)[idx] = o;
  } else if (b < 50000) {
    int e = (b - 37500) * 256 + threadIdx.x;
    if (e < EE) atomicAdd(&cntA[rA[e]], 1);
    else        atomicAdd(&cntB[rB[e - EE]], 1);
  } else {
    int idx = (b - 50000) * 256 + threadIdx.x;
    int n = idx / DIN, k = idx - n * DIN;
    const float* W = (n < 256) ? Wa : (n < 512) ? Wb : Wc;
    Wt[idx] = f2bf(W[(size_t)k * NH + (n & 255)]);
  }
}

// ---------------- 2-phase scan (both CSRs via blockIdx.y) ----------------
// phase 1: per-512-chunk scan; bsum gets raw block totals
__global__ __launch_bounds__(256) void scan1(int* __restrict__ cntA, int* __restrict__ rsA,
                                             int* __restrict__ cntB, int* __restrict__ rsB,
                                             int* __restrict__ bsum) {
  int* cnt = (blockIdx.y == 0) ? cntA : cntB;
  int* rs  = (blockIdx.y == 0) ? rsA  : rsB;
  int* bs  = bsum + blockIdx.y * 98;
  __shared__ int wsum[4];
  int t = threadIdx.x, lane = t & 63, wid = t >> 6;
  int i0 = blockIdx.x * 512 + 2 * t;
  int v0 = (i0 < NN) ? cnt[i0] : 0;
  int v1 = (i0 + 1 < NN) ? cnt[i0 + 1] : 0;
  int s = v0 + v1;
  int sc = s;
#pragma unroll
  for (int off = 1; off < 64; off <<= 1) {
    int tv = __shfl_up(sc, off, 64);
    if (lane >= off) sc += tv;
  }
  if (lane == 63) wsum[wid] = sc;
  __syncthreads();
  int woff = 0;
  for (int w = 0; w < wid; ++w) woff += wsum[w];
  int excl = woff + sc - s;
  if (i0 < NN)     { cnt[i0] = excl;          rs[i0 + 1] = excl + v0; }
  if (i0 + 1 < NN) { cnt[i0 + 1] = excl + v0; rs[i0 + 2] = excl + v0 + v1; }
  if (t == 255) bs[blockIdx.x] = woff + sc;
  if (blockIdx.x == 0 && t == 0) rs[0] = 0;
}

// phase 2: each block computes its own prefix of the 98 totals, adds offset
__global__ __launch_bounds__(512) void scan3(int* __restrict__ cntA, int* __restrict__ rsA,
                                             int* __restrict__ cntB, int* __restrict__ rsB,
                                             const int* __restrict__ bsum) {
  int* cnt = (blockIdx.y == 0) ? cntA : cntB;
  int* rs  = (blockIdx.y == 0) ? rsA  : rsB;
  __shared__ int bs[98];
  if (threadIdx.x < 98) bs[threadIdx.x] = bsum[blockIdx.y * 98 + threadIdx.x];
  __syncthreads();
  int off = 0;
  for (int k = 0; k < blockIdx.x; ++k) off += bs[k];
  int i = blockIdx.x * 512 + threadIdx.x;
  if (i < NN) { cnt[i] += off; rs[i + 1] += off; }
}

// ---------------- fused layer-1 MFMA GEMM + CSR scatter (4 edges/thread) ----------------
#define TM 128
#define TN 128
#define TK 32
#define GEMM_BLKS 2346           // 6 * 391
#define SCAT_BLKS 3125           // 3125 * 1024 = 3.2M edges
#define TOT_BLKS (GEMM_BLKS + SCAT_BLKS)

__device__ __forceinline__ void gload16(const u16* g, u16* lds) {
  __builtin_amdgcn_global_load_lds((const __attribute__((address_space(1))) unsigned int*)g,
                                   (__attribute__((address_space(3))) unsigned int*)lds, 16, 0, 0);
}

__global__ __launch_bounds__(256) void gemm_scatter(
    const u16* __restrict__ Xb, const u16* __restrict__ Wt, const float* __restrict__ mlp1_b,
    u16* __restrict__ H1, u16* __restrict__ H2, u16* __restrict__ T,
    const int* __restrict__ rA, const int* __restrict__ cA, const float* __restrict__ vA,
    const int* __restrict__ rB, const int* __restrict__ cB, const float* __restrict__ vB,
    int* __restrict__ curA, u32* __restrict__ edgeA,
    int* __restrict__ curB, u32* __restrict__ edgeB) {
  __shared__ u16 As[TM * TK];
  __shared__ u16 Bs[TN * TK];

  const int b = blockIdx.x;
  const int lo = (b * GEMM_BLKS) / TOT_BLKS;
  const int hi = ((b + 1) * GEMM_BLKS) / TOT_BLKS;

  if (hi > lo) {
    // ---- GEMM block ----
    const int gid = lo;
    const int tid = threadIdx.x;
    const int lane = tid & 63;
    const int w = tid >> 6;
    const int n0 = (gid % 6) * TN;
    const int m0 = (gid / 6) * TM;
    const int wm = w >> 1, wn = w & 1;

    f32x4 acc[4][4] = {};

    const int r_l = lane >> 2;
    const int kcp = lane & 3;
    const int r16 = lane & 15;
    const int kcl = lane >> 4;

    for (int k0 = 0; k0 < DIN; k0 += TK) {
#pragma unroll
      for (int q = 0; q < 2; ++q) {
        int row = w * 32 + q * 16 + r_l;
        int kc = kcp ^ ((row >> 1) & 3);
        int gr = m0 + row; if (gr >= NN) gr = NN - 1;
        gload16(Xb + (size_t)gr * DIN + k0 + kc * 8, &As[(w * 32 + q * 16) * TK]);
        gload16(Wt + (size_t)(n0 + row) * DIN + k0 + kc * 8, &Bs[(w * 32 + q * 16) * TK]);
      }
      __syncthreads();

      short8 aF[4], bF[4];
#pragma unroll
      for (int i = 0; i < 4; ++i) {
        int m = wm * 64 + i * 16 + r16;
        aF[i] = *reinterpret_cast<const short8*>(&As[m * TK + (kcl ^ ((m >> 1) & 3)) * 8]);
        int n = wn * 64 + i * 16 + r16;
        bF[i] = *reinterpret_cast<const short8*>(&Bs[n * TK + (kcl ^ ((n >> 1) & 3)) * 8]);
      }
#pragma unroll
      for (int i = 0; i < 4; ++i)
#pragma unroll
        for (int j = 0; j < 4; ++j)
          acc[i][j] = __builtin_amdgcn_mfma_f32_16x16x32_bf16(aF[i], bF[j], acc[i][j], 0, 0, 0);
      __syncthreads();
    }

    const int bsel = n0 >> 8;
    u16* O = (bsel == 0) ? H1 : (bsel == 1) ? H2 : T;
    const int act = (bsel == 2);
    const int cb = n0 & 255;
    const int rq = lane >> 4;
#pragma unroll
    for (int i = 0; i < 4; ++i) {
#pragma unroll
      for (int rr = 0; rr < 4; ++rr) {
        int grow = m0 + wm * 64 + i * 16 + rq * 4 + rr;
        if (grow >= NN) continue;
#pragma unroll
        for (int j = 0; j < 4; ++j) {
          int c = cb + wn * 64 + j * 16 + r16;
          float v = acc[i][j][rr];
          if (act) v = tanhf(v + mlp1_b[c]);
          O[(size_t)grow * NH + c] = f2bf(v);
        }
      }
    }
  } else {
    // ---- scatter block: 4 edges/thread, 4 independent atomic->store chains ----
    const int sid = b - lo;            // [0, SCAT_BLKS)
    const int base = sid * 1024 + threadIdx.x;
    int rws[4]; u32 pks[4];
#pragma unroll
    for (int q = 0; q < 4; ++q) {
      int e = base + q * 256;
      rws[q] = (e < EE) ? rA[e] : rB[e - EE];
    }
#pragma unroll
    for (int q = 0; q < 4; ++q) {
      int e = base + q * 256;
      if (e < EE) pks[q] = (u32)(u16)cA[e] | ((u32)f2bf(vA[e]) << 16);
      else        pks[q] = (u32)(u16)cB[e - EE] | ((u32)f2bf(vB[e - EE]) << 16);
    }
#pragma unroll
    for (int q = 0; q < 4; ++q) {
      int e = base + q * 256;
      if (e < EE) { int p = atomicAdd(&curA[rws[q]], 1); edgeA[p] = pks[q]; }
      else        { int p = atomicAdd(&curB[rws[q]], 1); edgeB[p] = pks[q]; }
    }
  }
}

// ---------------- fused SpMM(A)+SpMM(B)+attention+layer-2 GEMV ----------------
// 1 wave = 1 node. 8-deep 16 B gather pipeline per CSR (4-deep + 1-deep tails).
__global__ __launch_bounds__(256) void spmm_fuse(
    const int* __restrict__ rsA, const u32* __restrict__ edgeA,
    const u16* __restrict__ H1, const float* __restrict__ b1,
    const int* __restrict__ rsB, const u32* __restrict__ edgeB,
    const u16* __restrict__ H2, const float* __restrict__ b2,
    const u16* __restrict__ T, const float* __restrict__ afw,
    const float* __restrict__ W2r1, const float* __restrict__ W2r2,
    const float* __restrict__ mlpW, const float* __restrict__ mlpb,
    float* __restrict__ Z1, float* __restrict__ Z2, float* __restrict__ Y1) {
  __shared__ float w[DIN * 3];
  __shared__ float w1[NH * 2], w2[NH * 2], wmm[NH * 2];
  int tid = threadIdx.x;
  for (int i = tid; i < DIN * 3; i += 256) w[i] = afw[i];
  for (int i = tid; i < NH * 2; i += 256) { w1[i] = W2r1[i]; w2[i] = W2r2[i]; wmm[i] = mlpW[i]; }
  __syncthreads();

  int lane = tid & 63, wv = tid >> 6;
  int n = blockIdx.x * 4 + wv;
  int h0 = (lane & 31) * 8;
  int eg = lane >> 5;

  float ac1[8] = {}, ac2[8] = {};
  // ---- CSR-A gather ----
  {
    int s = rsA[n], e = rsA[n + 1];
    int i = s + eg;
    for (; i + 14 < e; i += 16) {           // 8-deep
      u32 ew[8];
#pragma unroll
      for (int q = 0; q < 8; ++q) ew[q] = edgeA[i + 2 * q];
      short8 hv[8];
#pragma unroll
      for (int q = 0; q < 8; ++q)
        hv[q] = *reinterpret_cast<const short8*>(H1 + (size_t)(ew[q] & 0xFFFF) * NH + h0);
#pragma unroll
      for (int q = 0; q < 8; ++q) {
        float f = bf2f((u16)(ew[q] >> 16));
#pragma unroll
        for (int j = 0; j < 8; ++j) ac1[j] += f * bf2f((u16)hv[q][j]);
      }
    }
    for (; i + 6 < e; i += 8) {             // 4-deep tail
      u32 ew[4];
#pragma unroll
      for (int q = 0; q < 4; ++q) ew[q] = edgeA[i + 2 * q];
      short8 hv[4];
#pragma unroll
      for (int q = 0; q < 4; ++q)
        hv[q] = *reinterpret_cast<const short8*>(H1 + (size_t)(ew[q] & 0xFFFF) * NH + h0);
#pragma unroll
      for (int q = 0; q < 4; ++q) {
        float f = bf2f((u16)(ew[q] >> 16));
#pragma unroll
        for (int j = 0; j < 8; ++j) ac1[j] += f * bf2f((u16)hv[q][j]);
      }
    }
    for (; i < e; i += 2) {                 // singles
      u32 e0 = edgeA[i];
      short8 v0 = *reinterpret_cast<const short8*>(H1 + (size_t)(e0 & 0xFFFF) * NH + h0);
      float f0 = bf2f((u16)(e0 >> 16));
#pragma unroll
      for (int j = 0; j < 8; ++j) ac1[j] += f0 * bf2f((u16)v0[j]);
    }
  }
  // ---- CSR-B gather ----
  {
    int s = rsB[n], e = rsB[n + 1];
    int i = s + eg;
    for (; i + 14 < e; i += 16) {
      u32 ew[8];
#pragma unroll
      for (int q = 0; q < 8; ++q) ew[q] = edgeB[i + 2 * q];
      short8 hv[8];
#pragma unroll
      for (int q = 0; q < 8; ++q)
        hv[q] = *reinterpret_cast<const short8*>(H2 + (size_t)(ew[q] & 0xFFFF) * NH + h0);
#pragma unroll
      for (int q = 0; q < 8; ++q) {
        float f = bf2f((u16)(ew[q] >> 16));
#pragma unroll
        for (int j = 0; j < 8; ++j) ac2[j] += f * bf2f((u16)hv[q][j]);
      }
    }
    for (; i + 6 < e; i += 8) {
      u32 ew[4];
#pragma unroll
      for (int q = 0; q < 4; ++q) ew[q] = edgeB[i + 2 * q];
      short8 hv[4];
#pragma unroll
      for (int q = 0; q < 4; ++q)
        hv[q] = *reinterpret_cast<const short8*>(H2 + (size_t)(ew[q] & 0xFFFF) * NH + h0);
#pragma unroll
      for (int q = 0; q < 4; ++q) {
        float f = bf2f((u16)(ew[q] >> 16));
#pragma unroll
        for (int j = 0; j < 8; ++j) ac2[j] += f * bf2f((u16)hv[q][j]);
      }
    }
    for (; i < e; i += 2) {
      u32 e0 = edgeB[i];
      short8 v0 = *reinterpret_cast<const short8*>(H2 + (size_t)(e0 & 0xFFFF) * NH + h0);
      float f0 = bf2f((u16)(e0 >> 16));
#pragma unroll
      for (int j = 0; j < 8; ++j) ac2[j] += f0 * bf2f((u16)v0[j]);
    }
  }
#pragma unroll
  for (int j = 0; j < 8; ++j) {
    ac1[j] += __shfl_xor(ac1[j], 32, 64);
    ac2[j] += __shfl_xor(ac2[j], 32, 64);
  }

  // + bias, T row
  float r1[8], r2[8], t8[8];
  {
    float4 bA0 = *reinterpret_cast<const float4*>(b1 + h0);
    float4 bA1 = *reinterpret_cast<const float4*>(b1 + h0 + 4);
    float4 bB0 = *reinterpret_cast<const float4*>(b2 + h0);
    float4 bB1 = *reinterpret_cast<const float4*>(b2 + h0 + 4);
    float bbA[8] = {bA0.x, bA0.y, bA0.z, bA0.w, bA1.x, bA1.y, bA1.z, bA1.w};
    float bbB[8] = {bB0.x, bB0.y, bB0.z, bB0.w, bB1.x, bB1.y, bB1.z, bB1.w};
    short8 tv = *reinterpret_cast<const short8*>(T + (size_t)n * NH + h0);
#pragma unroll
    for (int j = 0; j < 8; ++j) {
      r1[j] = ac1[j] + bbA[j];
      r2[j] = ac2[j] + bbB[j];
      t8[j] = bf2f((u16)tv[j]);
    }
  }

  // attention logits
  float l0 = 0.f, l1 = 0.f, l2 = 0.f;
#pragma unroll
  for (int k = 0; k < 8; ++k) {
    int h = h0 + k;
    l0 += r1[k] * w[h * 3 + 0] + r2[k] * w[(NH + h) * 3 + 0] + t8[k] * w[(2 * NH + h) * 3 + 0];
    l1 += r1[k] * w[h * 3 + 1] + r2[k] * w[(NH + h) * 3 + 1] + t8[k] * w[(2 * NH + h) * 3 + 1];
    l2 += r1[k] * w[h * 3 + 2] + r2[k] * w[(NH + h) * 3 + 2] + t8[k] * w[(2 * NH + h) * 3 + 2];
  }
#pragma unroll
  for (int off = 16; off > 0; off >>= 1) {
    l0 += __shfl_xor(l0, off, 64);
    l1 += __shfl_xor(l1, off, 64);
    l2 += __shfl_xor(l2, off, 64);
  }
  l0 = fabsf(l0); l1 = fabsf(l1); l2 = fabsf(l2);
  float mx = fmaxf(l0, fmaxf(l1, l2));
  float e0 = expf(l0 - mx), e1 = expf(l1 - mx), e2 = expf(l2 - mx);
  float inv = 1.f / (e0 + e1 + e2);
  float s0 = e0 * inv, s1 = e1 * inv, s2 = e2 * inv;

  // layer-2 GEMV on in-register x1
  float p10 = 0.f, p11 = 0.f, p20 = 0.f, p21 = 0.f, p30 = 0.f, p31 = 0.f;
#pragma unroll
  for (int k = 0; k < 8; ++k) {
    int h = h0 + k;
    float xv = s0 * r1[k] + s1 * r2[k] + s2 * t8[k];
    p10 += xv * w1[h * 2 + 0]; p11 += xv * w1[h * 2 + 1];
    p20 += xv * w2[h * 2 + 0]; p21 += xv * w2[h * 2 + 1];
    p30 += xv * wmm[h * 2 + 0]; p31 += xv * wmm[h * 2 + 1];
  }
#pragma unroll
  for (int off = 16; off > 0; off >>= 1) {
    p10 += __shfl_xor(p10, off, 64); p11 += __shfl_xor(p11, off, 64);
    p20 += __shfl_xor(p20, off, 64); p21 += __shfl_xor(p21, off, 64);
    p30 += __shfl_xor(p30, off, 64); p31 += __shfl_xor(p31, off, 64);
  }
  if (lane == 0) {
    Z1[n * 2 + 0] = p10; Z1[n * 2 + 1] = p11;
    Z2[n * 2 + 0] = p20; Z2[n * 2 + 1] = p21;
    Y1[n * 2 + 0] = tanhf(p30 + mlpb[0]);
    Y1[n * 2 + 1] = tanhf(p31 + mlpb[1]);
  }
}

// ---------------- layer-2 SpMM (2 cols) + final sum: half-wave per CSR ----------------
__global__ __launch_bounds__(256) void spmm2_final(
    const int* __restrict__ rsA, const u32* __restrict__ edgeA,
    const int* __restrict__ rsB, const u32* __restrict__ edgeB,
    const float* __restrict__ Z1, const float* __restrict__ Z2, const float* __restrict__ Y1,
    const float* __restrict__ b2r1, const float* __restrict__ b2r2,
    float* __restrict__ out) {
  int tid = threadIdx.x;
  int lane = tid & 63, wave = tid >> 6;
  int n = blockIdx.x * 4 + wave;
  int half = lane >> 5, l32 = lane & 31;
  const int* rs = half ? rsB : rsA;
  const u32* edge = half ? edgeB : edgeA;
  const float* Z = half ? Z2 : Z1;
  float a0 = 0.f, a1 = 0.f;
  int s = rs[n], e = rs[n + 1];
  int i = s + l32;
  for (; i + 32 < e; i += 64) {   // 2-deep
    u32 e0 = edge[i], e1 = edge[i + 32];
    float v0 = bf2f((u16)(e0 >> 16)), v1 = bf2f((u16)(e1 >> 16));
    float2 z0 = *reinterpret_cast<const float2*>(Z + (e0 & 0xFFFF) * 2);
    float2 z1 = *reinterpret_cast<const float2*>(Z + (e1 & 0xFFFF) * 2);
    a0 += v0 * z0.x + v1 * z1.x;
    a1 += v0 * z0.y + v1 * z1.y;
  }
  if (i < e) {
    u32 e0 = edge[i];
    float v0 = bf2f((u16)(e0 >> 16));
    float2 z0 = *reinterpret_cast<const float2*>(Z + (e0 & 0xFFFF) * 2);
    a0 += v0 * z0.x; a1 += v0 * z0.y;
  }
#pragma unroll
  for (int off = 16; off > 0; off >>= 1) {   // reduce within each 32-lane half
    a0 += __shfl_xor(a0, off, 64);
    a1 += __shfl_xor(a1, off, 64);
  }
  float bsum0 = __shfl(a0, 32, 64);
  float bsum1 = __shfl(a1, 32, 64);
  if (lane == 0) {
    out[n * 2 + 0] = (a0 + b2r1[0]) + (bsum0 + b2r2[0]) + Y1[n * 2 + 0];
    out[n * 2 + 1] = (a1 + b2r1[1]) + (bsum1 + b2r2[1]) + Y1[n * 2 + 1];
  }
}

extern "C" void kernel_launch(void* const* d_in, const int* in_sizes, int n_in,
                              void* d_out, int out_size, void* d_ws, size_t ws_size,
                              hipStream_t stream) {
  const float* x        = (const float*)d_in[0];
  const int*   adj_rows = (const int*)d_in[1];
  const int*   adj_cols = (const int*)d_in[2];
  const float* adj_vals = (const float*)d_in[3];
  const int*   s_rows   = (const int*)d_in[4];
  const int*   s_cols   = (const int*)d_in[5];
  const float* s_vals   = (const float*)d_in[6];
  const float* W1r1     = (const float*)d_in[7];
  const float* b1r1     = (const float*)d_in[8];
  const float* W1r2     = (const float*)d_in[9];
  const float* b1r2     = (const float*)d_in[10];
  const float* mlp1_W   = (const float*)d_in[11];
  const float* mlp1_b   = (const float*)d_in[12];
  const float* af1_w    = (const float*)d_in[13];
  const float* W2r1     = (const float*)d_in[14];
  const float* b2r1     = (const float*)d_in[15];
  const float* W2r2     = (const float*)d_in[16];
  const float* b2r2     = (const float*)d_in[17];
  const float* mlp2_W   = (const float*)d_in[18];
  const float* mlp2_b   = (const float*)d_in[19];
  float* out = (float*)d_out;

  char* p = (char*)d_ws;
  auto alloc = [&](size_t b) { char* r = p; p += (b + 255) & ~(size_t)255; return r; };

  // Xb region (76.8 MB) is dead after gemm; Z1/Z2/Y1 alias into it.
  char* xb_region = alloc((size_t)NN * DIN * 2);
  u16* Xb = (u16*)xb_region;
  float* Z1 = (float*)xb_region;
  float* Z2 = (float*)(xb_region + (size_t)NN * 2 * 4);
  float* Y1 = (float*)(xb_region + (size_t)NN * 4 * 4);

  u16* H1 = (u16*)alloc((size_t)NN * NH * 2);
  u16* H2 = (u16*)alloc((size_t)NN * NH * 2);
  u16* T  = (u16*)alloc((size_t)NN * NH * 2);
  u16* Wt = (u16*)alloc((size_t)DIN * DIN * 2);
  int* rsA   = (int*)alloc((size_t)(NN + 1) * 4);
  int* curA  = (int*)alloc((size_t)NN * 4);
  u32* edgeA = (u32*)alloc((size_t)EE * 4);
  int* rsB   = (int*)alloc((size_t)(NN + 1) * 4);
  int* curB  = (int*)alloc((size_t)NN * 4);
  u32* edgeB = (u32*)alloc((size_t)EE * 4);
  int* bsum  = (int*)alloc(2 * 98 * 4);

  // counters zero + fused prep (convert_x | hist | pack_wt)
  hipMemsetAsync(curA, 0, (size_t)NN * 4, stream);
  hipMemsetAsync(curB, 0, (size_t)NN * 4, stream);
  prep_kernel<<<52304, 256, 0, stream>>>(x, Xb, adj_rows, s_rows, curA, curB,
                                         W1r1, W1r2, mlp1_W, Wt);

  // 2-phase scan -> rs + exclusive cursors (both CSRs)
  dim3 gsc(98, 2);
  scan1<<<gsc, 256, 0, stream>>>(curA, rsA, curB, rsB, bsum);
  scan3<<<dim3(98, 2), 512, 0, stream>>>(curA, rsA, curB, rsB, bsum);

  // fused layer-1 GEMM + CSR scatter (interleaved, 4 edges/thread)
  gemm_scatter<<<TOT_BLKS, 256, 0, stream>>>(Xb, Wt, mlp1_b, H1, H2, T,
                                             adj_rows, adj_cols, adj_vals,
                                             s_rows, s_cols, s_vals,
                                             curA, edgeA, curB, edgeB);

  // fused SpMM(A)+SpMM(B)+attention+layer-2 GEMV
  spmm_fuse<<<NN / 4, 256, 0, stream>>>(rsA, edgeA, H1, b1r1,
                                        rsB, edgeB, H2, b1r2,
                                        T, af1_w, W2r1, W2r2, mlp2_W, mlp2_b,
                                        Z1, Z2, Y1);

  // layer-2 SpMMs + final sum
  spmm2_final<<<NN / 4, 256, 0, stream>>>(rsA, edgeA, rsB, edgeB,
                                          Z1, Z2, Y1, b2r1, b2r2, out);
}